// Round 2
// baseline (11177.249 us; speedup 1.0000x reference)
//
#include <hip/hip_runtime.h>
#include <hip/hip_bf16.h>

#define Bz 128
#define Tz 512
#define Hz 512
#define NG 8                    // batch groups
#define BG 16                   // batches per group
#define SL 16                   // h-columns per slice
#define NWAVE 6
#define NTHR (NWAVE * 64)
#define SIXH (6 * Hz)
#define PARITY_STRIDE (NG * BG * Hz)   // 65536 u32 per parity

typedef __bf16 bf16x8 __attribute__((ext_vector_type(8)));
typedef float f32x4 __attribute__((ext_vector_type(4)));
typedef unsigned int u32;
typedef u32 u32x2v __attribute__((ext_vector_type(2)));
typedef u32 u32x4v __attribute__((ext_vector_type(4)));

__device__ __forceinline__ u32x4v ld_coh_x4(const u32* p) {
  u32x4v r;
  asm volatile("global_load_dwordx4 %0, %1, off sc0 sc1" : "=v"(r) : "v"(p) : "memory");
  return r;
}
__device__ __forceinline__ void vm_wait0() {
  asm volatile("s_waitcnt vmcnt(0)" ::: "memory");
  __builtin_amdgcn_sched_barrier(0);
}
__device__ __forceinline__ float sigf(float x) { return 1.f / (1.f + __expf(-x)); }
__device__ __forceinline__ float tanh_f(float x) { return 2.f / (1.f + __expf(-2.f * x)) - 1.f; }
__device__ __forceinline__ u32 pk_bf16(float a, float b) {
  unsigned short lo = __builtin_bit_cast(unsigned short, (__bf16)a);
  unsigned short hi = __builtin_bit_cast(unsigned short, (__bf16)b);
  return (u32)lo | ((u32)hi << 16);
}

__global__ void lstm_init(u32* hb) {
  int i = blockIdx.x * blockDim.x + threadIdx.x;          // 65536 threads
  __hip_atomic_store(hb + i, 0xFFFE0000u, __ATOMIC_RELAXED, __HIP_MEMORY_SCOPE_AGENT);
  __hip_atomic_store(hb + PARITY_STRIDE + i, 0xFFFF0000u, __ATOMIC_RELAXED, __HIP_MEMORY_SCOPE_AGENT);
}

__global__ __launch_bounds__(NTHR) void lstm_main(
    const float* __restrict__ x, const int* __restrict__ lens,
    const float* __restrict__ Wg, const float* __restrict__ bg,
    float* __restrict__ out, u32* __restrict__ hb)
{
  const int tid = threadIdx.x;
  const int l   = tid & 63;
  const int w   = tid >> 6;          // wave id = gate chunk (0..4 gates, 5 = px5)
  const int wg  = blockIdx.x;
  const int gi  = wg & 7;            // batch group
  const int si  = wg >> 3;           // column slice 0..31
  const int oct = l >> 4;
  const int lm  = l & 15;

  __shared__ __align__(16) char xs[2][BG * Hz * 2];   // 2 x 16 KB bf16 x-tiles
  __shared__ __align__(16) char hs[BG * Hz * 2];      // 16 KB bf16 h-tile
  __shared__ float gs[NWAVE][BG][SL];                 // 6 KB gate exchange

  // ---- resident W fragments: wave w owns W[:, w*512 + si*16 + (0..15)] ----
  const int colg = w * Hz + si * SL + lm;
  bf16x8 wf[16];
#pragma unroll
  for (int s = 0; s < 16; ++s) {
#pragma unroll
    for (int j = 0; j < 8; ++j) {
      wf[s][j] = (__bf16)Wg[(size_t)(32 * s + 8 * oct + j) * SIXH + colg];
    }
  }
  const float bv = bg[colg];
  const float bias = (w < 5) ? 2.f * bv : bv;   // ref adds b_in in BOTH projections

  // ---- element-wise persistent state (threads 0..255 own (batch,col)) ----
  const int erow = tid >> 4;   // batch within group
  const int ecol = tid & 15;
  float cc = 0.f;
  int mylen = 0;
  if (tid < 256) mylen = lens[gi * BG + erow];

  // ---- prologue: stage x tile for t=0 ----
  if (tid < 256) {
    const float* xr = x + ((size_t)(gi * BG + erow) * Tz + 0) * Hz + ecol * 32;
#pragma unroll
    for (int q = 0; q < 8; ++q) {
      float a0 = xr[4 * q + 0], a1 = xr[4 * q + 1], a2 = xr[4 * q + 2], a3 = xr[4 * q + 3];
      int byte = (erow * 1024 + ecol * 64 + 8 * q) ^ ((erow & 7) << 4);
      u32x2v v; v.x = pk_bf16(a0, a1); v.y = pk_bf16(a2, a3);
      *(u32x2v*)(&xs[0][byte]) = v;
    }
  }
  __syncthreads();

  for (int t = 0; t < Tz; ++t) {
    // ---- [A] issue tagged h polls (h_{t-1}, parity (t-1)&1) ----
    u32x4v p0, p1, p2, p3, p4, p5, p6, p7;
    const u32* hrd = hb + ((size_t)((t + 1) & 1) * NG + gi) * (BG * Hz) + erow * Hz + ecol * 32;
    if (tid < 256) {
      p0 = ld_coh_x4(hrd + 0);  p1 = ld_coh_x4(hrd + 4);
      p2 = ld_coh_x4(hrd + 8);  p3 = ld_coh_x4(hrd + 12);
      p4 = ld_coh_x4(hrd + 16); p5 = ld_coh_x4(hrd + 20);
      p6 = ld_coh_x4(hrd + 24); p7 = ld_coh_x4(hrd + 28);
    }
    // ---- x-half MFMAs (overlaps h L3 latency) ----
    f32x4 acc0; acc0[0] = bias; acc0[1] = bias; acc0[2] = bias; acc0[3] = bias;
    f32x4 acc1; acc1[0] = 0.f; acc1[1] = 0.f; acc1[2] = 0.f; acc1[3] = 0.f;
    {
      const char* xb = xs[t & 1];
#pragma unroll
      for (int s = 0; s < 16; ++s) {
        int byte = (lm * 1024 + 64 * s + 16 * oct) ^ ((lm & 7) << 4);
        bf16x8 a = *(const bf16x8*)(xb + byte);
        if (s & 1) acc1 = __builtin_amdgcn_mfma_f32_16x16x32_bf16(a, wf[s], acc1, 0, 0, 0);
        else       acc0 = __builtin_amdgcn_mfma_f32_16x16x32_bf16(a, wf[s], acc0, 0, 0, 0);
      }
    }
    // ---- [B] complete polls, strip tags, stage h into LDS ----
    if (tid < 256) {
      vm_wait0();
      const u32 etag = (u32)((t - 1) & 0xffff);
#define BAD4(v) ((((v).x >> 16) != etag) | (((v).y >> 16) != etag) | (((v).z >> 16) != etag) | (((v).w >> 16) != etag))
      bool anybad = BAD4(p0) | BAD4(p1) | BAD4(p2) | BAD4(p3) | BAD4(p4) | BAD4(p5) | BAD4(p6) | BAD4(p7);
      int guard = 0;
      while (__builtin_expect(anybad, 0)) {
        __builtin_amdgcn_s_sleep(2);
        p0 = ld_coh_x4(hrd + 0);  p1 = ld_coh_x4(hrd + 4);
        p2 = ld_coh_x4(hrd + 8);  p3 = ld_coh_x4(hrd + 12);
        p4 = ld_coh_x4(hrd + 16); p5 = ld_coh_x4(hrd + 20);
        p6 = ld_coh_x4(hrd + 24); p7 = ld_coh_x4(hrd + 28);
        vm_wait0();
        anybad = BAD4(p0) | BAD4(p1) | BAD4(p2) | BAD4(p3) | BAD4(p4) | BAD4(p5) | BAD4(p6) | BAD4(p7);
        if (++guard > 50000) break;   // never trips unless true deadlock
      }
#undef BAD4
#define WRH(bi, v) { int byte = (erow * 1024 + ecol * 64 + 8 * (bi)) ^ ((erow & 7) << 4); \
      u32x2v pv; pv.x = ((v).x & 0xffffu) | ((v).y << 16); pv.y = ((v).z & 0xffffu) | ((v).w << 16); \
      *(u32x2v*)(&hs[byte]) = pv; }
      WRH(0, p0) WRH(1, p1) WRH(2, p2) WRH(3, p3)
      WRH(4, p4) WRH(5, p5) WRH(6, p6) WRH(7, p7)
#undef WRH
    }
    __syncthreads();   // barrier-1: h tile ready
    // ---- h-half MFMAs (same W rows, K2 in [512,1024)) ----
    if (w < 5) {
#pragma unroll
      for (int s = 0; s < 16; ++s) {
        int byte = (lm * 1024 + 64 * s + 16 * oct) ^ ((lm & 7) << 4);
        bf16x8 a = *(const bf16x8*)(hs + byte);
        if (s & 1) acc1 = __builtin_amdgcn_mfma_f32_16x16x32_bf16(a, wf[s], acc1, 0, 0, 0);
        else       acc0 = __builtin_amdgcn_mfma_f32_16x16x32_bf16(a, wf[s], acc0, 0, 0, 0);
      }
    }
    f32x4 g = acc0 + acc1;
#pragma unroll
    for (int r = 0; r < 4; ++r) gs[w][oct * 4 + r][lm] = g[r];
    // ---- x prefetch for t+1 (overlaps) ----
    if (tid < 256 && t + 1 < Tz) {
      const float* xr = x + ((size_t)(gi * BG + erow) * Tz + (t + 1)) * Hz + ecol * 32;
#pragma unroll
      for (int q = 0; q < 8; ++q) {
        float a0 = xr[4 * q + 0], a1 = xr[4 * q + 1], a2 = xr[4 * q + 2], a3 = xr[4 * q + 3];
        int byte = (erow * 1024 + ecol * 64 + 8 * q) ^ ((erow & 7) << 4);
        u32x2v v; v.x = pk_bf16(a0, a1); v.y = pk_bf16(a2, a3);
        *(u32x2v*)(&xs[(t + 1) & 1][byte]) = v;
      }
    }
    __syncthreads();   // barrier-2: gates + next x tile ready
    // ---- element-wise LSTM cell + highway ----
    if (tid < 256) {
      float g0 = gs[0][erow][ecol], g1 = gs[1][erow][ecol], g2 = gs[2][erow][ecol];
      float g3 = gs[3][erow][ecol], g4 = gs[4][erow][ecol], px5 = gs[5][erow][ecol];
      float ig = sigf(g0), fg = sigf(g1), mg = tanh_f(g2), og = sigf(g3), hg = sigf(g4);
      float cn = ig * mg + fg * cc;
      float ot = og * tanh_f(cn);
      ot = hg * ot + (1.f - hg) * px5;
      bool act = t < mylen;
      float hv = act ? ot : 0.f;
      cc = act ? cn : 0.f;
      out[((size_t)(gi * BG + erow) * Tz + t) * Hz + si * SL + ecol] = hv;   // f32 output
      unsigned short hbits = __builtin_bit_cast(unsigned short, (__bf16)hv);
      u32* hwp = hb + ((size_t)(t & 1) * NG + gi) * (BG * Hz) + erow * Hz + si * SL + ecol;
      __hip_atomic_store(hwp, ((u32)(t & 0xffff) << 16) | (u32)hbits,
                         __ATOMIC_RELEASE, __HIP_MEMORY_SCOPE_AGENT);
    }
  }
}

extern "C" void kernel_launch(void* const* d_in, const int* in_sizes, int n_in,
                              void* d_out, int out_size, void* d_ws, size_t ws_size,
                              hipStream_t stream) {
  const float* x  = (const float*)d_in[0];
  const int* lens = (const int*)d_in[1];      // jax x64 disabled -> int32
  const float* Wg = (const float*)d_in[2];
  const float* bg = (const float*)d_in[3];
  float* out = (float*)d_out;                 // reference output dtype: float32
  u32* hb = (u32*)d_ws;                       // 512 KB tagged h exchange

  hipLaunchKernelGGL(lstm_init, dim3(256), dim3(256), 0, stream, hb);
  // 256 blocks, <=54KB LDS, 384 threads: all co-resident on 256 CUs with a
  // plain launch (>=1 block/CU by resource limits). No cooperative launch —
  // it can poison graph capture if it errors mid-capture.
  hipLaunchKernelGGL(lstm_main, dim3(256), dim3(NTHR), 0, stream,
                     x, lens, Wg, bg, out, hb);
}

// Round 4
// 5159.026 us; speedup vs baseline: 2.1665x; 2.1665x over previous
//
#include <hip/hip_runtime.h>
#include <hip/hip_bf16.h>

#define Tz 512
#define Hz 512
#define NG 8                    // batch groups
#define BG 16                   // batches per group
#define SL 16                   // h-columns per slice
#define NWAVE 6
#define NTHR (NWAVE * 64)
#define SIXH (6 * Hz)
#define HB_U32 4096             // per (parity,group): 16x512 bf16 = 4096 u32
#define CNT_OFF (2 * NG * HB_U32)   // u32 offset of step counters in ws

typedef __bf16 bf16x8 __attribute__((ext_vector_type(8)));
typedef float f32x4 __attribute__((ext_vector_type(4)));
typedef unsigned int u32;
typedef u32 u32x4v __attribute__((ext_vector_type(4)));

__device__ __forceinline__ u32x4v ld_coh_x4(const u32* p) {
  u32x4v r;
  asm volatile("global_load_dwordx4 %0, %1, off sc0 sc1" : "=v"(r) : "v"(p) : "memory");
  return r;
}
__device__ __forceinline__ void st_coh_u32(u32* p, u32 v) {
  asm volatile("global_store_dword %0, %1, off sc0 sc1" :: "v"(p), "v"(v) : "memory");
}
__device__ __forceinline__ void vm_wait0() {
  asm volatile("s_waitcnt vmcnt(0)" ::: "memory");
  __builtin_amdgcn_sched_barrier(0);
}
__device__ __forceinline__ float sigf(float x) { return 1.f / (1.f + __expf(-x)); }
__device__ __forceinline__ float tanh_f(float x) { return 2.f / (1.f + __expf(-2.f * x)) - 1.f; }
__device__ __forceinline__ u32 pk_bf16(float a, float b) {
  unsigned short lo = __builtin_bit_cast(unsigned short, (__bf16)a);
  unsigned short hi = __builtin_bit_cast(unsigned short, (__bf16)b);
  return (u32)lo | ((u32)hi << 16);
}

__global__ void lstm_init(u32* ws) {
  int i = blockIdx.x * blockDim.x + threadIdx.x;   // 4096 threads zero counters
  st_coh_u32(ws + CNT_OFF + i, 0u);
}

__global__ __launch_bounds__(NTHR) void lstm_main(
    const float* __restrict__ x, const int* __restrict__ lens,
    const float* __restrict__ Wg, const float* __restrict__ bg,
    float* __restrict__ out, u32* __restrict__ hb)
{
  const int tid = threadIdx.x;
  const int l   = tid & 63;
  const int w   = tid >> 6;          // wave id = gate chunk (0..4 gates, 5 = px5)
  const int wg  = blockIdx.x;
  const int gi  = wg & 7;            // batch group
  const int si  = wg >> 3;           // column slice 0..31
  const int oct = l >> 4;
  const int lm  = l & 15;
  u32* cnt = hb + CNT_OFF;           // cnt[gi*Tz + t], monotonic arrivals

  __shared__ __align__(16) char xs[2][BG * Hz * 2];   // 2 x 16 KB bf16 x-tiles
  __shared__ __align__(16) char hs[BG * Hz * 2];      // 16 KB bf16 h-tile
  __shared__ float gs[NWAVE][BG][SL];                 // 6 KB gate exchange

  // ---- resident W fragments: wave w owns W[:, w*512 + si*16 + (0..15)] ----
  const int colg = w * Hz + si * SL + lm;
  bf16x8 wf[16];
#pragma unroll
  for (int s = 0; s < 16; ++s) {
#pragma unroll
    for (int j = 0; j < 8; ++j) {
      wf[s][j] = (__bf16)Wg[(size_t)(32 * s + 8 * oct + j) * SIXH + colg];
    }
  }
  const float bv = bg[colg];
  const float bias = (w < 5) ? 2.f * bv : bv;   // ref adds b_in in BOTH projections

  const int erow = tid >> 4;   // batch within group (tid<256 view)
  const int ecol = tid & 15;
  float cc = 0.f;
  int mylen = 0;
  if (tid < 256) mylen = lens[gi * BG + erow];

  // ---- prologue: stage x tile for t=0 ----
  if (tid < 256) {
    const float4* xr = (const float4*)(x + ((size_t)(gi * BG + erow) * Tz + 0) * Hz + ecol * 32);
    float4 f[8];
#pragma unroll
    for (int q = 0; q < 8; ++q) f[q] = xr[q];
#pragma unroll
    for (int Q = 0; Q < 4; ++Q) {
      u32x4v v = { pk_bf16(f[2*Q].x, f[2*Q].y),   pk_bf16(f[2*Q].z, f[2*Q].w),
                   pk_bf16(f[2*Q+1].x, f[2*Q+1].y), pk_bf16(f[2*Q+1].z, f[2*Q+1].w) };
      int byte = (erow * 1024 + ecol * 64 + 16 * Q) ^ ((erow & 7) << 4);
      *(u32x4v*)(&xs[0][byte]) = v;
    }
  }
  __syncthreads();

  for (int t = 0; t < Tz; ++t) {
    // ---- [A] x-half MFMAs (no cross-block dependency) ----
    f32x4 acc0; acc0[0] = bias; acc0[1] = bias; acc0[2] = bias; acc0[3] = bias;
    f32x4 acc1; acc1[0] = 0.f; acc1[1] = 0.f; acc1[2] = 0.f; acc1[3] = 0.f;
    {
      const char* xb = xs[t & 1];
#pragma unroll
      for (int s = 0; s < 16; ++s) {
        int byte = (lm * 1024 + 64 * s + 16 * oct) ^ ((lm & 7) << 4);
        bf16x8 a = *(const bf16x8*)(xb + byte);
        if (s & 1) acc1 = __builtin_amdgcn_mfma_f32_16x16x32_bf16(a, wf[s], acc1, 0, 0, 0);
        else       acc0 = __builtin_amdgcn_mfma_f32_16x16x32_bf16(a, wf[s], acc0, 0, 0, 0);
      }
    }
    // ---- [B] wait for all 32 producer blocks of step t-1 (one lane polls) ----
    if (t > 0) {
      if (tid == 0) {
        u32* cp = cnt + gi * Tz + (t - 1);
        int guard = 0;
        while (__hip_atomic_load(cp, __ATOMIC_RELAXED, __HIP_MEMORY_SCOPE_AGENT) < 32u) {
          if (++guard > 2000000) break;   // finite on catastrophe; never trips normally
        }
        // ordering: one acquire load so subsequent data reads can't be stale
        (void)__hip_atomic_load(cp, __ATOMIC_ACQUIRE, __HIP_MEMORY_SCOPE_AGENT);
      }
      __syncthreads();
    }
    // ---- [C] fetch group h (16 KB, once), prefetch x(t+1); stage both to LDS ----
    {
      u32x4v h0, h1, h2, h3;
      float4 f[8];
      const bool do_h = (t > 0) && (tid < 256);
      const bool do_x = (tid < 256) && (t + 1 < Tz);
      if (do_h) {
        const u32* hp = hb + ((size_t)((t + 1) & 1) * NG + gi) * HB_U32 + tid * 16;
        h0 = ld_coh_x4(hp + 0); h1 = ld_coh_x4(hp + 4);
        h2 = ld_coh_x4(hp + 8); h3 = ld_coh_x4(hp + 12);
      }
      if (do_x) {
        const float4* xr = (const float4*)(x + ((size_t)(gi * BG + erow) * Tz + (t + 1)) * Hz + ecol * 32);
#pragma unroll
        for (int q = 0; q < 8; ++q) f[q] = xr[q];
      }
      if (tid < 256) vm_wait0();
      if (do_h) {
        int b0 = (erow * 1024 + ecol * 64) ^ ((erow & 7) << 4);
        *(u32x4v*)(&hs[b0 ^ 0])  = h0;   // XOR by 16*q keeps 16B chunks contiguous
        *(u32x4v*)(&hs[b0 ^ 16]) = h1;
        *(u32x4v*)(&hs[b0 ^ 32]) = h2;
        *(u32x4v*)(&hs[b0 ^ 48]) = h3;
      }
      if (do_x) {
#pragma unroll
        for (int Q = 0; Q < 4; ++Q) {
          u32x4v v = { pk_bf16(f[2*Q].x, f[2*Q].y),   pk_bf16(f[2*Q].z, f[2*Q].w),
                       pk_bf16(f[2*Q+1].x, f[2*Q+1].y), pk_bf16(f[2*Q+1].z, f[2*Q+1].w) };
          int byte = (erow * 1024 + ecol * 64 + 16 * Q) ^ ((erow & 7) << 4);
          *(u32x4v*)(&xs[(t + 1) & 1][byte]) = v;
        }
      }
    }
    __syncthreads();   // h tile + next x tile ready
    // ---- [D] h-half MFMAs ----
    if (w < 5 && t > 0) {
#pragma unroll
      for (int s = 0; s < 16; ++s) {
        int byte = (lm * 1024 + 64 * s + 16 * oct) ^ ((lm & 7) << 4);
        bf16x8 a = *(const bf16x8*)(hs + byte);
        if (s & 1) acc1 = __builtin_amdgcn_mfma_f32_16x16x32_bf16(a, wf[s], acc1, 0, 0, 0);
        else       acc0 = __builtin_amdgcn_mfma_f32_16x16x32_bf16(a, wf[s], acc0, 0, 0, 0);
      }
    }
    {
      f32x4 g = acc0 + acc1;
#pragma unroll
      for (int r = 0; r < 4; ++r) gs[w][oct * 4 + r][lm] = g[r];
    }
    __syncthreads();   // gates ready
    // ---- [E] elementwise cell + highway; publish h slice; arrive (release) ----
    float hv = 0.f;
    if (tid < 256) {
      float g0 = gs[0][erow][ecol], g1 = gs[1][erow][ecol], g2 = gs[2][erow][ecol];
      float g3 = gs[3][erow][ecol], g4 = gs[4][erow][ecol], px5 = gs[5][erow][ecol];
      float ig = sigf(g0), fg = sigf(g1), mg = tanh_f(g2), og = sigf(g3), hg = sigf(g4);
      float cn = ig * mg + fg * cc;
      float ot = og * tanh_f(cn);
      ot = hg * ot + (1.f - hg) * px5;
      bool act = t < mylen;
      hv = act ? ot : 0.f;
      cc = act ? cn : 0.f;
      u32 hb32 = (u32)__builtin_bit_cast(unsigned short, (__bf16)hv);
      u32 nb = __shfl_xor(hb32, 1, 64);          // neighbor column's bits
      if (!(ecol & 1)) {
        u32 pv = hb32 | (nb << 16);              // cols (c, c+1) packed
        u32* hp = hb + ((size_t)(t & 1) * NG + gi) * HB_U32
                     + erow * 256 + si * 8 + (ecol >> 1);
        st_coh_u32(hp, pv);                       // write-through toward MALL
      }
      vm_wait0();                                 // stores at least in local L2
    }
    __syncthreads();
    if (tid == 0) {
      // RELEASE: compiler emits the full agent-release fence (incl. L2
      // writeback to the MALL coherence point) before the RMW, covering the
      // data stores drained above by all producer waves.
      __hip_atomic_fetch_add(cnt + gi * Tz + t, 1u,
                             __ATOMIC_RELEASE, __HIP_MEMORY_SCOPE_AGENT);
    }
    if (tid < 256) {
      out[((size_t)(gi * BG + erow) * Tz + t) * Hz + si * SL + ecol] = hv;
    }
  }
}

extern "C" void kernel_launch(void* const* d_in, const int* in_sizes, int n_in,
                              void* d_out, int out_size, void* d_ws, size_t ws_size,
                              hipStream_t stream) {
  const float* x  = (const float*)d_in[0];
  const int* lens = (const int*)d_in[1];      // jax x64 disabled -> int32
  const float* Wg = (const float*)d_in[2];
  const float* bg = (const float*)d_in[3];
  float* out = (float*)d_out;                 // reference output dtype: float32
  u32* hb = (u32*)d_ws;                       // 256KB h exchange + 16KB counters

  hipLaunchKernelGGL(lstm_init, dim3(16), dim3(256), 0, stream, hb);
  // 256 blocks / 256 CUs, 55KB LDS, 384 thr -> all resident; monotonic
  // counters + proper release/acquire make the exchange safe regardless of
  // scheduling anyway.
  hipLaunchKernelGGL(lstm_main, dim3(256), dim3(NTHR), 0, stream,
                     x, lens, Wg, bg, out, hb);
}

// Round 5
// 2764.911 us; speedup vs baseline: 4.0425x; 1.8659x over previous
//
#include <hip/hip_runtime.h>
#include <hip/hip_bf16.h>

#define Tz 512
#define Hz 512
#define NG 8                    // batch groups
#define BG 16                   // batches per group
#define SL 16                   // h-columns per slice
#define NWAVE 6
#define NTHR (NWAVE * 64)
#define SIXH (6 * Hz)
#define HB_U32 (BG * Hz)        // per (parity,group): 16x512 tagged u32 = 32 KB
#define CNT_OFF (2 * NG * HB_U32)   // u32 offset of step counters in ws
#define WS_U32 (CNT_OFF + NG * Tz)  // total initialized u32 (528 KB)

typedef __bf16 bf16x8 __attribute__((ext_vector_type(8)));
typedef float f32x4 __attribute__((ext_vector_type(4)));
typedef unsigned int u32;
typedef u32 u32x4v __attribute__((ext_vector_type(4)));

__device__ __forceinline__ u32x4v ld_coh_x4(const u32* p) {
  u32x4v r;
  asm volatile("global_load_dwordx4 %0, %1, off sc0 sc1" : "=v"(r) : "v"(p) : "memory");
  return r;
}
__device__ __forceinline__ void st_coh_u32(u32* p, u32 v) {
  asm volatile("global_store_dword %0, %1, off sc0 sc1" :: "v"(p), "v"(v) : "memory");
}
__device__ __forceinline__ void vm_wait0() {
  asm volatile("s_waitcnt vmcnt(0)" ::: "memory");
  __builtin_amdgcn_sched_barrier(0);
}
__device__ __forceinline__ float sigf(float x) { return 1.f / (1.f + __expf(-x)); }
__device__ __forceinline__ float tanh_f(float x) { return 2.f / (1.f + __expf(-2.f * x)) - 1.f; }
__device__ __forceinline__ u32 pk_bf16(float a, float b) {
  unsigned short lo = __builtin_bit_cast(unsigned short, (__bf16)a);
  unsigned short hi = __builtin_bit_cast(unsigned short, (__bf16)b);
  return (u32)lo | ((u32)hi << 16);
}

// Pre-fill exchange buffer with sentinel tags (0xFFFF != any t) and zero the
// arrival counters. Kernel-end implicit flush makes this MALL-visible before
// lstm_main starts (stream order).
__global__ void lstm_init(u32* ws) {
  int i = blockIdx.x * blockDim.x + threadIdx.x;   // WS_U32 threads
  ws[i] = (i < CNT_OFF) ? 0xFFFF0000u : 0u;
}

__global__ __launch_bounds__(NTHR) void lstm_main(
    const float* __restrict__ x, const int* __restrict__ lens,
    const float* __restrict__ Wg, const float* __restrict__ bg,
    float* __restrict__ out, u32* __restrict__ hb)
{
  const int tid = threadIdx.x;
  const int l   = tid & 63;
  const int w   = tid >> 6;          // wave id = gate chunk (0..4 gates, 5 = px5)
  const int wg  = blockIdx.x;
  const int gi  = wg & 7;            // batch group (round-robin -> same XCD, locality)
  const int si  = wg >> 3;           // column slice 0..31
  const int oct = l >> 4;
  const int lm  = l & 15;
  u32* cnt = hb + CNT_OFF;           // cnt[gi*Tz + t], monotonic arrival hints

  __shared__ __align__(16) char xs[2][BG * Hz * 2];   // 2 x 16 KB bf16 x-tiles
  __shared__ __align__(16) char hs[BG * Hz * 2];      // 16 KB bf16 h-tile
  __shared__ float gs[NWAVE][BG][SL];                 // 6 KB gate exchange

  // ---- resident W fragments: wave w owns W[:, w*512 + si*16 + (0..15)] ----
  const int colg = w * Hz + si * SL + lm;
  bf16x8 wf[16];
#pragma unroll
  for (int s = 0; s < 16; ++s) {
#pragma unroll
    for (int j = 0; j < 8; ++j) {
      wf[s][j] = (__bf16)Wg[(size_t)(32 * s + 8 * oct + j) * SIXH + colg];
    }
  }
  const float bv = bg[colg];
  const float bias = (w < 5) ? 2.f * bv : bv;   // ref adds b_in in BOTH projections

  const int erow = tid >> 4;   // batch within group (tid<256 view)
  const int ecol = tid & 15;
  float cc = 0.f;
  int mylen = 0;
  if (tid < 256) mylen = lens[gi * BG + erow];

  // ---- prologue: stage x tile for t=0 ----
  if (tid < 256) {
    const float4* xr = (const float4*)(x + ((size_t)(gi * BG + erow) * Tz + 0) * Hz + ecol * 32);
    float4 f[8];
#pragma unroll
    for (int q = 0; q < 8; ++q) f[q] = xr[q];
#pragma unroll
    for (int Q = 0; Q < 4; ++Q) {
      u32x4v v = { pk_bf16(f[2*Q].x, f[2*Q].y),   pk_bf16(f[2*Q].z, f[2*Q].w),
                   pk_bf16(f[2*Q+1].x, f[2*Q+1].y), pk_bf16(f[2*Q+1].z, f[2*Q+1].w) };
      int byte = (erow * 1024 + ecol * 64 + 16 * Q) ^ ((erow & 7) << 4);
      *(u32x4v*)(&xs[0][byte]) = v;
    }
  }
  __syncthreads();

  for (int t = 0; t < Tz; ++t) {
    // ---- [A] x-half MFMAs (no cross-block dependency; overlaps peers' publish) ----
    f32x4 acc0; acc0[0] = bias; acc0[1] = bias; acc0[2] = bias; acc0[3] = bias;
    f32x4 acc1; acc1[0] = 0.f; acc1[1] = 0.f; acc1[2] = 0.f; acc1[3] = 0.f;
    {
      const char* xb = xs[t & 1];
#pragma unroll
      for (int s = 0; s < 16; ++s) {
        int byte = (lm * 1024 + 64 * s + 16 * oct) ^ ((lm & 7) << 4);
        bf16x8 a = *(const bf16x8*)(xb + byte);
        if (s & 1) acc1 = __builtin_amdgcn_mfma_f32_16x16x32_bf16(a, wf[s], acc1, 0, 0, 0);
        else       acc0 = __builtin_amdgcn_mfma_f32_16x16x32_bf16(a, wf[s], acc0, 0, 0, 0);
      }
    }
    // ---- [B] arrival hint: one lane polls step-(t-1) counter (relaxed, no fence) ----
    if (t > 0) {
      if (tid == 0) {
        u32* cp = cnt + gi * Tz + (t - 1);
        int guard = 0;
        while (__hip_atomic_load(cp, __ATOMIC_RELAXED, __HIP_MEMORY_SCOPE_AGENT) < 32u) {
          if (++guard > 4000000) break;   // finite on catastrophe only
        }
      }
      __syncthreads();
    }
    // ---- [C] bulk tagged h read (self-validating) + x(t+1) prefetch; stage to LDS ----
    {
      const bool do_h = (t > 0) && (tid < 256);
      const bool do_x = (tid < 256) && (t + 1 < Tz);
      const int r  = erow;            // this thread stages h row r, cols [c0,c0+32)
      const int c0 = ecol * 32;
      u32x4v hv4[8];
      float4 f[8];
      const u32* hp = hb + ((size_t)((t + 1) & 1) * NG + gi) * HB_U32 + r * Hz + c0;
      if (do_h) {
#pragma unroll
        for (int q = 0; q < 8; ++q) hv4[q] = ld_coh_x4(hp + 4 * q);
      }
      if (do_x) {
        const float4* xr = (const float4*)(x + ((size_t)(gi * BG + erow) * Tz + (t + 1)) * Hz + ecol * 32);
#pragma unroll
        for (int q = 0; q < 8; ++q) f[q] = xr[q];
      }
      if (tid < 256) vm_wait0();
      if (do_h) {
        const u32 etag = (u32)(t - 1);
        bool bad = false;
#pragma unroll
        for (int q = 0; q < 8; ++q)
#pragma unroll
          for (int j = 0; j < 4; ++j) bad |= ((hv4[q][j] >> 16) != etag);
        int guard = 0;
        while (__builtin_expect(bad, 0)) {        // rare: store-ack vs MALL lag
#pragma unroll
          for (int q = 0; q < 8; ++q) hv4[q] = ld_coh_x4(hp + 4 * q);
          vm_wait0();
          bad = false;
#pragma unroll
          for (int q = 0; q < 8; ++q)
#pragma unroll
            for (int j = 0; j < 4; ++j) bad |= ((hv4[q][j] >> 16) != etag);
          if (++guard > 500000) break;
        }
        // strip tags, pack pairs, store 4x16B to swizzled LDS
#pragma unroll
        for (int k2 = 0; k2 < 4; ++k2) {
          u32x4v o;
#pragma unroll
          for (int m = 0; m < 4; ++m) {
            int c = 8 * k2 + 2 * m;
            o[m] = (hv4[c >> 2][c & 3] & 0xffffu) | (hv4[(c + 1) >> 2][(c + 1) & 3] << 16);
          }
          int byte = (r * 1024 + c0 * 2 + 16 * k2) ^ ((r & 7) << 4);
          *(u32x4v*)(&hs[byte]) = o;
        }
      }
      if (do_x) {
#pragma unroll
        for (int Q = 0; Q < 4; ++Q) {
          u32x4v v = { pk_bf16(f[2*Q].x, f[2*Q].y),   pk_bf16(f[2*Q].z, f[2*Q].w),
                       pk_bf16(f[2*Q+1].x, f[2*Q+1].y), pk_bf16(f[2*Q+1].z, f[2*Q+1].w) };
          int byte = (erow * 1024 + ecol * 64 + 16 * Q) ^ ((erow & 7) << 4);
          *(u32x4v*)(&xs[(t + 1) & 1][byte]) = v;
        }
      }
    }
    __syncthreads();   // h tile + next x tile ready
    // ---- [D] h-half MFMAs ----
    if (w < 5 && t > 0) {
#pragma unroll
      for (int s = 0; s < 16; ++s) {
        int byte = (lm * 1024 + 64 * s + 16 * oct) ^ ((lm & 7) << 4);
        bf16x8 a = *(const bf16x8*)(hs + byte);
        if (s & 1) acc1 = __builtin_amdgcn_mfma_f32_16x16x32_bf16(a, wf[s], acc1, 0, 0, 0);
        else       acc0 = __builtin_amdgcn_mfma_f32_16x16x32_bf16(a, wf[s], acc0, 0, 0, 0);
      }
    }
    {
      f32x4 g = acc0 + acc1;
#pragma unroll
      for (int r = 0; r < 4; ++r) gs[w][oct * 4 + r][lm] = g[r];
    }
    __syncthreads();   // gates ready
    // ---- [E] elementwise cell + highway; publish tagged h; arrive (no fence) ----
    float hv = 0.f;
    if (tid < 256) {
      float g0 = gs[0][erow][ecol], g1 = gs[1][erow][ecol], g2 = gs[2][erow][ecol];
      float g3 = gs[3][erow][ecol], g4 = gs[4][erow][ecol], px5 = gs[5][erow][ecol];
      float ig = sigf(g0), fg = sigf(g1), mg = tanh_f(g2), og = sigf(g3), hg = sigf(g4);
      float cn = ig * mg + fg * cc;
      float ot = og * tanh_f(cn);
      ot = hg * ot + (1.f - hg) * px5;
      bool act = t < mylen;
      hv = act ? ot : 0.f;
      cc = act ? cn : 0.f;
      u32 hbits = (u32)__builtin_bit_cast(unsigned short, (__bf16)hv);
      u32* hp = hb + ((size_t)(t & 1) * NG + gi) * HB_U32 + erow * Hz + si * SL + ecol;
      st_coh_u32(hp, ((u32)t << 16) | hbits);     // tag+payload in one dword
      vm_wait0();                                  // acked before arrival hint
    }
    __syncthreads();
    if (tid == 0) {
      __hip_atomic_fetch_add(cnt + gi * Tz + t, 1u,
                             __ATOMIC_RELAXED, __HIP_MEMORY_SCOPE_AGENT);
    }
    if (tid < 256) {
      out[((size_t)(gi * BG + erow) * Tz + t) * Hz + si * SL + ecol] = hv;
    }
  }
}

extern "C" void kernel_launch(void* const* d_in, const int* in_sizes, int n_in,
                              void* d_out, int out_size, void* d_ws, size_t ws_size,
                              hipStream_t stream) {
  const float* x  = (const float*)d_in[0];
  const int* lens = (const int*)d_in[1];      // jax x64 disabled -> int32
  const float* Wg = (const float*)d_in[2];
  const float* bg = (const float*)d_in[3];
  float* out = (float*)d_out;                 // reference output dtype: float32
  u32* hb = (u32*)d_ws;                       // 512KB tagged h exchange + 16KB counters

  hipLaunchKernelGGL(lstm_init, dim3(WS_U32 / 256), dim3(256), 0, stream, hb);
  hipLaunchKernelGGL(lstm_main, dim3(256), dim3(NTHR), 0, stream,
                     x, lens, Wg, bg, out, hb);
}